// Round 2
// baseline (895.670 us; speedup 1.0000x reference)
//
#include <hip/hip_runtime.h>
#include <hip/hip_bf16.h>

#define B 32
#define A 32768
#define G 64
#define C 91
#define NBINS 2048

typedef unsigned long long ull;

// ---------------- workspace layout (bytes) ----------------
static constexpr size_t offMatched = 0;                     // B*A*4
static constexpr size_t offBits    = (size_t)B * A * 4;     // packed loss bits
static constexpr size_t offNumFg   = (size_t)2 * B * A * 4; // B*4
static constexpr size_t offAcc     = offNumFg + B * 4;      // 3 doubles
static constexpr size_t offTick    = offAcc + 3 * 8;        // 2 ints
static constexpr size_t offGt      = offTick + 8;           // B*G ull (8-aligned)
static constexpr int    ZERO_N     = (int)((offGt - offNumFg) / 4);  // 40

// ---------------- init ----------------
__global__ void init_kernel(int* zero_base, ull* gtpack) {
  int i = blockIdx.x * 256 + threadIdx.x;
  if (i < ZERO_N) zero_base[i] = 0;
  if (i < B * G) gtpack[i] = 0xFFFFFFFFull;
}

// ---------------- match (+fused force via ticket) ----------------
__global__ __launch_bounds__(256) void match_kernel(
    const float4* __restrict__ anchors, const float4* __restrict__ gt_boxes,
    int* __restrict__ matched, ull* __restrict__ gtpack, int* __restrict__ ticket) {
#pragma clang fp contract(off)
  int b = blockIdx.y;
  int a = blockIdx.x * 256 + threadIdx.x;
  __shared__ float4 gtb[G];
  __shared__ float gtarea[G];
  __shared__ ull best[G];
  __shared__ int lastBlk;
  if (threadIdx.x < G) {
    float4 g = gt_boxes[b * G + threadIdx.x];
    gtb[threadIdx.x] = g;
    gtarea[threadIdx.x] = (g.z - g.x) * (g.w - g.y);
    best[threadIdx.x] = 0ull;
  }
  __syncthreads();
  float4 an = anchors[(size_t)b * A + a];
  float area_a = (an.z - an.x) * (an.w - an.y);
  float bestv = -1.0f;
  int bestg = 0;
  for (int g = 0; g < G; ++g) {
    float4 gb = gtb[g];
    float tlx = fmaxf(gb.x, an.x), tly = fmaxf(gb.y, an.y);
    float brx = fminf(gb.z, an.z), bry = fminf(gb.w, an.w);
    float w = fmaxf(brx - tlx, 0.0f), h = fmaxf(bry - tly, 0.0f);
    float inter = w * h;
    float iou = 0.0f;
    if (inter > 0.0f) iou = inter / (gtarea[g] + area_a - inter + 1e-16f);
    if (iou > bestv) { bestv = iou; bestg = g; }
    if (iou > 0.0f) {
      ull p = ((ull)__float_as_uint(iou) << 32) | (unsigned)(~(unsigned)a);
      if (p > best[g]) atomicMax(&best[g], p);
    }
  }
  matched[(size_t)b * A + a] = (bestv < 0.45f) ? -1 : bestg;
  __syncthreads();
  if (threadIdx.x < G) {
    ull p = best[threadIdx.x];
    if (p) atomicMax(&gtpack[b * G + threadIdx.x], p);
  }
  // ---- fused force: last block replays the per-b serial override ----
  __threadfence();          // each thread's matched write -> device scope
  __syncthreads();
  if (threadIdx.x == 0)
    lastBlk = (atomicAdd(ticket, 1) == (int)(gridDim.x * gridDim.y) - 1);
  __syncthreads();
  if (lastBlk && threadIdx.x < B) {
    int bb = threadIdx.x;
    for (int g = 0; g < G; ++g) {        // ascending g: last-wins tie order
      ull p = atomicAdd(&gtpack[bb * G + g], 0ull);  // coherent read
      unsigned aa = ~(unsigned)(p & 0xFFFFFFFFull);
      matched[(size_t)bb * A + aa] = g;
    }
  }
}

// ---------------- fused softmax + decode + giou ----------------
// Block = 256 threads owns NT=8 contiguous 64-anchor tiles. Double-buffered
// LDS (2x23.3 KB -> 3 blocks/CU). Staging via __builtin_amdgcn_global_load_lds
// (width 16): no VGPR/scratch round trip. Writes PACKED loss bits: fg -> 0u
// (sentinel; exactly-safe in the radix select, see select_fused).
#define APB 64
#define NT 8
#define NF4 (APB * C / 4)               // 1456 float4 per tile
#define NSTG 6                          // ceil(1456/256)
#define TAILN (NF4 - (NSTG - 1) * 256)  // 176

__device__ __forceinline__ void stage_tile(const float4* src, float* dst, int tid) {
  int wbase = tid & ~63;  // wave-uniform LDS base; HW adds lane*16
#pragma unroll
  for (int r = 0; r < NSTG - 1; ++r)
    __builtin_amdgcn_global_load_lds(
        (const __attribute__((address_space(1))) void*)(src + r * 256 + tid),
        (__attribute__((address_space(3))) void*)(dst + (r * 256 + wbase) * 4),
        16, 0, 0);
  if (tid < TAILN)
    __builtin_amdgcn_global_load_lds(
        (const __attribute__((address_space(1))) void*)(src + (NSTG - 1) * 256 + tid),
        (__attribute__((address_space(3))) void*)(dst + ((NSTG - 1) * 256 + wbase) * 4),
        16, 0, 0);
}

__global__ __launch_bounds__(256) void loss_kernel(
    const float4* __restrict__ logit4, const float4* __restrict__ reg,
    const float4* __restrict__ anchors, const float4* __restrict__ gt_boxes,
    const int* __restrict__ gt_labels, const int* __restrict__ matched,
    unsigned* __restrict__ cls_bits, int* __restrict__ num_fg, double* __restrict__ acc) {
  __shared__ float buf[2][APB * C];  // 2 x 23296 B
  __shared__ double rb[4], rf[4];
  __shared__ int rc[4];
  int tid = threadIdx.x;
  int b = blockIdx.y;
  int tile0 = blockIdx.x * NT;
  size_t bbase4 = (size_t)b * A * C / 4;
  int t4 = tid >> 2, q = tid & 3;

  stage_tile(logit4 + bbase4 + (size_t)tile0 * NF4, buf[0], tid);
  int mmCur = matched[(size_t)b * A + tile0 * APB + t4];
  int tclsCur = (mmCur >= 0) ? gt_labels[b * G + mmCur] : (C - 1);
  __syncthreads();  // drains vmcnt(0) -> buf[0] ready

  double bbs = 0.0, fgs = 0.0;
  int cnt = 0;

  for (int t = 0; t < NT; ++t) {
    int cur = t & 1;
    if (t + 1 < NT)
      stage_tile(logit4 + bbase4 + (size_t)(tile0 + t + 1) * NF4, buf[cur ^ 1], tid);
    int mmNext = 0, tclsNext = 0;
    if (t + 1 < NT) {
      mmNext = matched[(size_t)b * A + (tile0 + t + 1) * APB + t4];
      tclsNext = (mmNext >= 0) ? gt_labels[b * G + mmNext] : (C - 1);
    }
    {
      const float* BC = buf[cur];
      int a = (tile0 + t) * APB + t4;
      const float* row = BC + t4 * C + 23 * q;
      const int cn = (q < 3) ? 23 : 22;
      float s0 = 0.f, s1 = 0.f, s2 = 0.f, s3 = 0.f;
      int j = 0;
#pragma unroll
      for (; j + 4 <= 20; j += 4) {
        s0 += __expf(row[j]);
        s1 += __expf(row[j + 1]);
        s2 += __expf(row[j + 2]);
        s3 += __expf(row[j + 3]);
      }
      for (; j < cn; ++j) s0 += __expf(row[j]);
      float s = (s0 + s1) + (s2 + s3);
      s += __shfl_xor(s, 1);
      s += __shfl_xor(s, 2);
      float lse = __logf(s);
      float xt = BC[t4 * C + tclsCur];
      float loss = lse - xt;
      if (q == 0) {
        cls_bits[(size_t)b * A + a] = (mmCur >= 0) ? 0u : __float_as_uint(loss);
        if (mmCur >= 0) {
          fgs += (double)loss;
          cnt++;
          float4 an = anchors[(size_t)b * A + a];
          float4 rg = reg[(size_t)b * A + a];
          float4 gb = gt_boxes[b * G + mmCur];
          float w = an.z - an.x, h = an.w - an.y;
          float cx = an.x + 0.5f * w, cy = an.y + 0.5f * h;
          float dw = fminf(rg.z, 4.135166556742356f);
          float dh = fminf(rg.w, 4.135166556742356f);
          float pcx = rg.x * w + cx, pcy = rg.y * h + cy;
          float pw = expf(dw) * w, ph = expf(dh) * h;
          float px0 = pcx - 0.5f * pw, py0 = pcy - 0.5f * ph;
          float px1 = pcx + 0.5f * pw, py1 = pcy + 0.5f * ph;
          float tlx = fmaxf(px0, gb.x), tly = fmaxf(py0, gb.y);
          float brx = fminf(px1, gb.z), bry = fminf(py1, gb.w);
          float iw = fmaxf(brx - tlx, 0.f), ih = fmaxf(bry - tly, 0.f);
          float inter = iw * ih;
          float ap = (px1 - px0) * (py1 - py0);
          float ag = (gb.z - gb.x) * (gb.w - gb.y);
          float uni = ap + ag - inter + 1e-16f;
          float iou = inter / uni;
          float ctlx = fminf(px0, gb.x), ctly = fminf(py0, gb.y);
          float cbrx = fmaxf(px1, gb.z), cbry = fmaxf(py1, gb.w);
          float acr = (cbrx - ctlx) * (cbry - ctly);
          float giou = iou - (acr - uni) / fmaxf(acr, 1e-16f);
          giou = fminf(fmaxf(giou, -1.f), 1.f);
          bbs += (double)(1.f - giou);
        }
      }
    }
    mmCur = mmNext;
    tclsCur = tclsNext;
    __syncthreads();  // buf[cur] free to re-stage; vmcnt(0) drain readies other buf
  }

  int lane = tid & 63, wave = tid >> 6;
  for (int off = 32; off; off >>= 1) {
    bbs += __shfl_xor(bbs, off);
    fgs += __shfl_xor(fgs, off);
    cnt += __shfl_xor(cnt, off);
  }
  if (lane == 0) { rb[wave] = bbs; rf[wave] = fgs; rc[wave] = cnt; }
  __syncthreads();
  if (tid == 0) {
    double tb = rb[0] + rb[1] + rb[2] + rb[3];
    double tf = rf[0] + rf[1] + rf[2] + rf[3];
    int tc = rc[0] + rc[1] + rc[2] + rc[3];
    if (tb != 0.0) atomicAdd(&acc[0], tb);
    if (tf != 0.0) atomicAdd(&acc[1], tf);
    if (tc) atomicAdd(&num_fg[b], tc);
  }
}

// ---------------- fused 3-level radix select + bgsum + finalize ----------------
// One block per image b, 1024 threads. Each thread register-caches its 32
// packed loss words (fg anchors carry sentinel 0u = +0.0f: sentinel sits in
// bin 0 / value 0.0, which can only influence the result when T==0.0, where
// its r*T and v>T contributions are both exactly 0 -> bit-exact vs separate
// matched test). All histograms live in LDS; selection logic is verbatim
// the previous select_kernel. Last block (device ticket) finalizes out[].
__global__ __launch_bounds__(1024) void select_fused(
    const unsigned* __restrict__ bits, const int* __restrict__ num_fg,
    double* __restrict__ acc, int* __restrict__ ticket, float* __restrict__ out) {
  int b = blockIdx.x, tid = threadIdx.x;
  __shared__ int h[NBINS];
  __shared__ int gsum[256];
  __shared__ float sT;
  __shared__ int sDone, sKrem, sR;
  __shared__ unsigned sPref;
  __shared__ double sd[16];

  unsigned bv[32];
#pragma unroll
  for (int i = 0; i < 32; ++i) bv[i] = bits[(size_t)b * A + i * 1024 + tid];
  if (tid == 0) { sDone = 0; sR = 0; }

  // ---- level 1 ----
  for (int i = tid; i < NBINS; i += 1024) h[i] = 0;
  __syncthreads();
#pragma unroll
  for (int i = 0; i < 32; ++i) atomicAdd(&h[bv[i] >> 21], 1);
  __syncthreads();
  if (tid < 256) {
    int gs = 0;
#pragma unroll
    for (int j = 0; j < 8; ++j) gs += h[tid * 8 + j];
    gsum[tid] = gs;
  }
  __syncthreads();
  if (tid == 0) {
    int nf = num_fg[b];
    int k = 3 * nf;
    int bgcnt = A - nf;
    if (k <= 0) { sT = __builtin_inff(); sDone = 1; }
    else if (k >= bgcnt) { sT = -1.0f; sDone = 1; }
    else {
      int run = 0, gidx = 255;
      for (; gidx >= 0; --gidx) { if (run + gsum[gidx] >= k) break; run += gsum[gidx]; }
      if (gidx < 0) { sT = -1.0f; sDone = 1; }
      else {
        int bin = gidx * 8 + 7;
        for (; bin > gidx * 8; --bin) { if (run + h[bin] >= k) break; run += h[bin]; }
        sPref = (unsigned)bin; sKrem = k - run;
      }
    }
  }
  __syncthreads();

  if (!sDone) {  // block-uniform branch
    // ---- level 2 ----
    unsigned p1 = sPref;
    int k = sKrem;
    __syncthreads();
    for (int i = tid; i < NBINS; i += 1024) h[i] = 0;
    __syncthreads();
#pragma unroll
    for (int i = 0; i < 32; ++i)
      if ((bv[i] >> 21) == p1) atomicAdd(&h[(bv[i] >> 10) & 2047], 1);
    __syncthreads();
    if (tid < 256) {
      int gs = 0;
#pragma unroll
      for (int j = 0; j < 8; ++j) gs += h[tid * 8 + j];
      gsum[tid] = gs;
    }
    __syncthreads();
    if (tid == 0) {
      int run = 0, gidx = 255;
      for (; gidx >= 0; --gidx) { if (run + gsum[gidx] >= k) break; run += gsum[gidx]; }
      if (gidx < 0) { sT = -1.0f; sDone = 1; }
      else {
        int bin = gidx * 8 + 7;
        for (; bin > gidx * 8; --bin) { if (run + h[bin] >= k) break; run += h[bin]; }
        sPref = (p1 << 11) | (unsigned)bin; sKrem = k - run;
      }
    }
    __syncthreads();
  }
  if (!sDone) {
    // ---- level 3 ----
    unsigned p2 = sPref;
    int k = sKrem;
    __syncthreads();
    if (tid < 1024) h[tid] = 0;
    __syncthreads();
#pragma unroll
    for (int i = 0; i < 32; ++i)
      if ((bv[i] >> 10) == p2) atomicAdd(&h[bv[i] & 1023], 1);
    __syncthreads();
    if (tid < 256) {
      int gs = 0;
#pragma unroll
      for (int j = 0; j < 4; ++j) gs += h[tid * 4 + j];
      gsum[tid] = gs;
    }
    __syncthreads();
    if (tid == 0) {
      int run = 0, gidx = 255;
      for (; gidx >= 0; --gidx) { if (run + gsum[gidx] >= k) break; run += gsum[gidx]; }
      if (gidx < 0) { sT = -1.0f; }
      else {
        int bin = gidx * 4 + 3;
        for (; bin > gidx * 4; --bin) { if (run + h[bin] >= k) break; run += h[bin]; }
        sT = __uint_as_float((p2 << 10) | (unsigned)bin);
        sR = k - run;
      }
    }
    __syncthreads();
  }

  // ---- bg sum over threshold (+ r*T) ----
  float T = sT;
  float ls = 0.f;
#pragma unroll
  for (int i = 0; i < 32; ++i) {
    float v = __uint_as_float(bv[i]);
    if (v > T) ls += v;   // sentinel 0.0 adds exactly 0 when T<0
  }
  for (int off = 32; off; off >>= 1) ls += __shfl_xor(ls, off);
  if ((tid & 63) == 0) sd[tid >> 6] = (double)ls;
  __syncthreads();
  if (tid == 0) {
    double tt = 0.0;
    for (int w = 0; w < 16; ++w) tt += sd[w];
    if (sR > 0) tt += (double)sR * (double)sT;
    if (tt != 0.0) atomicAdd(&acc[2], tt);
    __threadfence();
    if (atomicAdd(ticket, 1) == B - 1) {
      // last block: finalize. acc[0..1]/num_fg written in a previous
      // dispatch (visible); acc[2] written by sibling blocks -> atomic read.
      int tot = 0;
      for (int bb = 0; bb < B; ++bb) tot += num_fg[bb];
      double N = (double)(tot > 1 ? tot : 1);
      double a2 = atomicAdd(&acc[2], 0.0);
      out[0] = (float)(2.0 * acc[0] / N);
      out[1] = (float)((acc[1] + a2) / N);
    }
  }
}

extern "C" void kernel_launch(void* const* d_in, const int* in_sizes, int n_in,
                              void* d_out, int out_size, void* d_ws, size_t ws_size,
                              hipStream_t stream) {
  const float4* logit4  = (const float4*)d_in[0];
  const float4* reg     = (const float4*)d_in[1];
  const float4* anchors = (const float4*)d_in[2];
  const float4* gtb     = (const float4*)d_in[3];
  const int*    gtl     = (const int*)d_in[4];

  char* ws = (char*)d_ws;
  int*      matched = (int*)(ws + offMatched);
  unsigned* cbits   = (unsigned*)(ws + offBits);
  int*      numfg   = (int*)(ws + offNumFg);
  double*   acc     = (double*)(ws + offAcc);
  int*      tick    = (int*)(ws + offTick);
  ull*      gtpack  = (ull*)(ws + offGt);
  float*    out     = (float*)d_out;

  init_kernel<<<8, 256, 0, stream>>>((int*)(ws + offNumFg), gtpack);
  match_kernel<<<dim3(A / 256, B), 256, 0, stream>>>(anchors, gtb, matched, gtpack, tick);
  loss_kernel<<<dim3(A / (APB * NT), B), 256, 0, stream>>>(
      logit4, reg, anchors, gtb, gtl, matched, cbits, numfg, acc);
  select_fused<<<B, 1024, 0, stream>>>(cbits, numfg, acc, tick + 1, out);
}

// Round 3
// 713.342 us; speedup vs baseline: 1.2556x; 1.2556x over previous
//
#include <hip/hip_runtime.h>
#include <hip/hip_bf16.h>

#define B 32
#define A 32768
#define G 64
#define C 91
#define NBINS 2048

typedef unsigned long long ull;

// ---------------- workspace layout (bytes) ----------------
static constexpr size_t offMatched = 0;                     // B*A*4
static constexpr size_t offBits    = (size_t)B * A * 4;     // packed loss bits
static constexpr size_t offNumFg   = (size_t)2 * B * A * 4; // B*4
static constexpr size_t offAcc     = offNumFg + B * 4;      // 3 doubles
static constexpr size_t offTick    = offAcc + 3 * 8;        // 2 ints
static constexpr size_t offGt      = offTick + 8;           // B*G ull (8-aligned)
static constexpr int    ZERO_N     = (int)((offGt - offNumFg) / 4);  // 40

// ---------------- init ----------------
__global__ void init_kernel(int* zero_base, ull* gtpack) {
  int i = blockIdx.x * 256 + threadIdx.x;
  if (i < ZERO_N) zero_base[i] = 0;
  if (i < B * G) gtpack[i] = 0xFFFFFFFFull;
}

// ---------------- match ----------------
// NOTE (round-2 post-mortem): do NOT fuse the force step here. It needs
// device-scope visibility of every block's matched[] writes; an in-kernel
// __threadfence() ticket costs ~280 us of L2 writeback across 4096 blocks
// (per-XCD L2s non-coherent). The dispatch boundary gives the same
// ordering for ~5 us.
__global__ __launch_bounds__(256) void match_kernel(
    const float4* __restrict__ anchors, const float4* __restrict__ gt_boxes,
    int* __restrict__ matched, ull* __restrict__ gtpack) {
#pragma clang fp contract(off)
  int b = blockIdx.y;
  int a = blockIdx.x * 256 + threadIdx.x;
  __shared__ float4 gtb[G];
  __shared__ float gtarea[G];
  __shared__ ull best[G];
  if (threadIdx.x < G) {
    float4 g = gt_boxes[b * G + threadIdx.x];
    gtb[threadIdx.x] = g;
    gtarea[threadIdx.x] = (g.z - g.x) * (g.w - g.y);
    best[threadIdx.x] = 0ull;
  }
  __syncthreads();
  float4 an = anchors[(size_t)b * A + a];
  float area_a = (an.z - an.x) * (an.w - an.y);
  float bestv = -1.0f;
  int bestg = 0;
  for (int g = 0; g < G; ++g) {
    float4 gb = gtb[g];
    float tlx = fmaxf(gb.x, an.x), tly = fmaxf(gb.y, an.y);
    float brx = fminf(gb.z, an.z), bry = fminf(gb.w, an.w);
    float w = fmaxf(brx - tlx, 0.0f), h = fmaxf(bry - tly, 0.0f);
    float inter = w * h;
    float iou = 0.0f;
    if (inter > 0.0f) iou = inter / (gtarea[g] + area_a - inter + 1e-16f);
    if (iou > bestv) { bestv = iou; bestg = g; }
    if (iou > 0.0f) {
      ull p = ((ull)__float_as_uint(iou) << 32) | (unsigned)(~(unsigned)a);
      if (p > best[g]) atomicMax(&best[g], p);
    }
  }
  matched[(size_t)b * A + a] = (bestv < 0.45f) ? -1 : bestg;
  __syncthreads();
  if (threadIdx.x < G) {
    ull p = best[threadIdx.x];
    if (p) atomicMax(&gtpack[b * G + threadIdx.x], p);
  }
}

// ---------------- force match (separate dispatch = free coherence) ----------------
__global__ void force_kernel(const ull* __restrict__ gtpack, int* __restrict__ matched) {
  int b = blockIdx.x * blockDim.x + threadIdx.x;
  if (b < B) {
    for (int g = 0; g < G; ++g) {   // ascending g: last-wins tie order
      unsigned a = ~(unsigned)(gtpack[b * G + g] & 0xFFFFFFFFull);
      matched[(size_t)b * A + a] = g;
    }
  }
}

// ---------------- fused softmax + decode + giou ----------------
// Block = 256 threads owns NT=8 contiguous 64-anchor tiles. Double-buffered
// LDS (2x23.3 KB -> 3 blocks/CU). Staging via __builtin_amdgcn_global_load_lds
// (width 16): no VGPR/scratch round trip. Writes PACKED loss bits: fg -> 0u
// (sentinel; exactly-safe in the radix select, see select_fused).
#define APB 64
#define NT 8
#define NF4 (APB * C / 4)               // 1456 float4 per tile
#define NSTG 6                          // ceil(1456/256)
#define TAILN (NF4 - (NSTG - 1) * 256)  // 176

__device__ __forceinline__ void stage_tile(const float4* src, float* dst, int tid) {
  int wbase = tid & ~63;  // wave-uniform LDS base; HW adds lane*16
#pragma unroll
  for (int r = 0; r < NSTG - 1; ++r)
    __builtin_amdgcn_global_load_lds(
        (const __attribute__((address_space(1))) void*)(src + r * 256 + tid),
        (__attribute__((address_space(3))) void*)(dst + (r * 256 + wbase) * 4),
        16, 0, 0);
  if (tid < TAILN)
    __builtin_amdgcn_global_load_lds(
        (const __attribute__((address_space(1))) void*)(src + (NSTG - 1) * 256 + tid),
        (__attribute__((address_space(3))) void*)(dst + ((NSTG - 1) * 256 + wbase) * 4),
        16, 0, 0);
}

__global__ __launch_bounds__(256) void loss_kernel(
    const float4* __restrict__ logit4, const float4* __restrict__ reg,
    const float4* __restrict__ anchors, const float4* __restrict__ gt_boxes,
    const int* __restrict__ gt_labels, const int* __restrict__ matched,
    unsigned* __restrict__ cls_bits, int* __restrict__ num_fg, double* __restrict__ acc) {
  __shared__ float buf[2][APB * C];  // 2 x 23296 B
  __shared__ double rb[4], rf[4];
  __shared__ int rc[4];
  int tid = threadIdx.x;
  int b = blockIdx.y;
  int tile0 = blockIdx.x * NT;
  size_t bbase4 = (size_t)b * A * C / 4;
  int t4 = tid >> 2, q = tid & 3;

  stage_tile(logit4 + bbase4 + (size_t)tile0 * NF4, buf[0], tid);
  int mmCur = matched[(size_t)b * A + tile0 * APB + t4];
  int tclsCur = (mmCur >= 0) ? gt_labels[b * G + mmCur] : (C - 1);
  __syncthreads();  // drains vmcnt(0) -> buf[0] ready

  double bbs = 0.0, fgs = 0.0;
  int cnt = 0;

  for (int t = 0; t < NT; ++t) {
    int cur = t & 1;
    if (t + 1 < NT)
      stage_tile(logit4 + bbase4 + (size_t)(tile0 + t + 1) * NF4, buf[cur ^ 1], tid);
    int mmNext = 0, tclsNext = 0;
    if (t + 1 < NT) {
      mmNext = matched[(size_t)b * A + (tile0 + t + 1) * APB + t4];
      tclsNext = (mmNext >= 0) ? gt_labels[b * G + mmNext] : (C - 1);
    }
    {
      const float* BC = buf[cur];
      int a = (tile0 + t) * APB + t4;
      const float* row = BC + t4 * C + 23 * q;
      const int cn = (q < 3) ? 23 : 22;
      float s0 = 0.f, s1 = 0.f, s2 = 0.f, s3 = 0.f;
      int j = 0;
#pragma unroll
      for (; j + 4 <= 20; j += 4) {
        s0 += __expf(row[j]);
        s1 += __expf(row[j + 1]);
        s2 += __expf(row[j + 2]);
        s3 += __expf(row[j + 3]);
      }
      for (; j < cn; ++j) s0 += __expf(row[j]);
      float s = (s0 + s1) + (s2 + s3);
      s += __shfl_xor(s, 1);
      s += __shfl_xor(s, 2);
      float lse = __logf(s);
      float xt = BC[t4 * C + tclsCur];
      float loss = lse - xt;
      if (q == 0) {
        cls_bits[(size_t)b * A + a] = (mmCur >= 0) ? 0u : __float_as_uint(loss);
        if (mmCur >= 0) {
          fgs += (double)loss;
          cnt++;
          float4 an = anchors[(size_t)b * A + a];
          float4 rg = reg[(size_t)b * A + a];
          float4 gb = gt_boxes[b * G + mmCur];
          float w = an.z - an.x, h = an.w - an.y;
          float cx = an.x + 0.5f * w, cy = an.y + 0.5f * h;
          float dw = fminf(rg.z, 4.135166556742356f);
          float dh = fminf(rg.w, 4.135166556742356f);
          float pcx = rg.x * w + cx, pcy = rg.y * h + cy;
          float pw = expf(dw) * w, ph = expf(dh) * h;
          float px0 = pcx - 0.5f * pw, py0 = pcy - 0.5f * ph;
          float px1 = pcx + 0.5f * pw, py1 = pcy + 0.5f * ph;
          float tlx = fmaxf(px0, gb.x), tly = fmaxf(py0, gb.y);
          float brx = fminf(px1, gb.z), bry = fminf(py1, gb.w);
          float iw = fmaxf(brx - tlx, 0.f), ih = fmaxf(bry - tly, 0.f);
          float inter = iw * ih;
          float ap = (px1 - px0) * (py1 - py0);
          float ag = (gb.z - gb.x) * (gb.w - gb.y);
          float uni = ap + ag - inter + 1e-16f;
          float iou = inter / uni;
          float ctlx = fminf(px0, gb.x), ctly = fminf(py0, gb.y);
          float cbrx = fmaxf(px1, gb.z), cbry = fmaxf(py1, gb.w);
          float acr = (cbrx - ctlx) * (cbry - ctly);
          float giou = iou - (acr - uni) / fmaxf(acr, 1e-16f);
          giou = fminf(fmaxf(giou, -1.f), 1.f);
          bbs += (double)(1.f - giou);
        }
      }
    }
    mmCur = mmNext;
    tclsCur = tclsNext;
    __syncthreads();  // buf[cur] free to re-stage; vmcnt(0) drain readies other buf
  }

  int lane = tid & 63, wave = tid >> 6;
  for (int off = 32; off; off >>= 1) {
    bbs += __shfl_xor(bbs, off);
    fgs += __shfl_xor(fgs, off);
    cnt += __shfl_xor(cnt, off);
  }
  if (lane == 0) { rb[wave] = bbs; rf[wave] = fgs; rc[wave] = cnt; }
  __syncthreads();
  if (tid == 0) {
    double tb = rb[0] + rb[1] + rb[2] + rb[3];
    double tf = rf[0] + rf[1] + rf[2] + rf[3];
    int tc = rc[0] + rc[1] + rc[2] + rc[3];
    if (tb != 0.0) atomicAdd(&acc[0], tb);
    if (tf != 0.0) atomicAdd(&acc[1], tf);
    if (tc) atomicAdd(&num_fg[b], tc);
  }
}

// ---------------- fused 3-level radix select + bgsum + finalize ----------------
// One block per image b, 1024 threads. Each thread register-caches its 32
// packed loss words (fg anchors carry sentinel 0u = +0.0f: sentinel sits in
// bin 0 / value 0.0, which can only influence the result when T==0.0, where
// its r*T and v>T contributions are both exactly 0 -> bit-exact vs separate
// matched test). All histograms live in LDS; selection logic is verbatim
// the original select_kernel. Last block (device ticket) finalizes out[].
// The ticket here is cheap: only B=32 blocks pay the fence, not 4096.
__global__ __launch_bounds__(1024) void select_fused(
    const unsigned* __restrict__ bits, const int* __restrict__ num_fg,
    double* __restrict__ acc, int* __restrict__ ticket, float* __restrict__ out) {
  int b = blockIdx.x, tid = threadIdx.x;
  __shared__ int h[NBINS];
  __shared__ int gsum[256];
  __shared__ float sT;
  __shared__ int sDone, sKrem, sR;
  __shared__ unsigned sPref;
  __shared__ double sd[16];

  unsigned bv[32];
#pragma unroll
  for (int i = 0; i < 32; ++i) bv[i] = bits[(size_t)b * A + i * 1024 + tid];
  if (tid == 0) { sDone = 0; sR = 0; }

  // ---- level 1 ----
  for (int i = tid; i < NBINS; i += 1024) h[i] = 0;
  __syncthreads();
#pragma unroll
  for (int i = 0; i < 32; ++i) atomicAdd(&h[bv[i] >> 21], 1);
  __syncthreads();
  if (tid < 256) {
    int gs = 0;
#pragma unroll
    for (int j = 0; j < 8; ++j) gs += h[tid * 8 + j];
    gsum[tid] = gs;
  }
  __syncthreads();
  if (tid == 0) {
    int nf = num_fg[b];
    int k = 3 * nf;
    int bgcnt = A - nf;
    if (k <= 0) { sT = __builtin_inff(); sDone = 1; }
    else if (k >= bgcnt) { sT = -1.0f; sDone = 1; }
    else {
      int run = 0, gidx = 255;
      for (; gidx >= 0; --gidx) { if (run + gsum[gidx] >= k) break; run += gsum[gidx]; }
      if (gidx < 0) { sT = -1.0f; sDone = 1; }
      else {
        int bin = gidx * 8 + 7;
        for (; bin > gidx * 8; --bin) { if (run + h[bin] >= k) break; run += h[bin]; }
        sPref = (unsigned)bin; sKrem = k - run;
      }
    }
  }
  __syncthreads();

  if (!sDone) {  // block-uniform branch
    // ---- level 2 ----
    unsigned p1 = sPref;
    int k = sKrem;
    __syncthreads();
    for (int i = tid; i < NBINS; i += 1024) h[i] = 0;
    __syncthreads();
#pragma unroll
    for (int i = 0; i < 32; ++i)
      if ((bv[i] >> 21) == p1) atomicAdd(&h[(bv[i] >> 10) & 2047], 1);
    __syncthreads();
    if (tid < 256) {
      int gs = 0;
#pragma unroll
      for (int j = 0; j < 8; ++j) gs += h[tid * 8 + j];
      gsum[tid] = gs;
    }
    __syncthreads();
    if (tid == 0) {
      int run = 0, gidx = 255;
      for (; gidx >= 0; --gidx) { if (run + gsum[gidx] >= k) break; run += gsum[gidx]; }
      if (gidx < 0) { sT = -1.0f; sDone = 1; }
      else {
        int bin = gidx * 8 + 7;
        for (; bin > gidx * 8; --bin) { if (run + h[bin] >= k) break; run += h[bin]; }
        sPref = (p1 << 11) | (unsigned)bin; sKrem = k - run;
      }
    }
    __syncthreads();
  }
  if (!sDone) {
    // ---- level 3 ----
    unsigned p2 = sPref;
    int k = sKrem;
    __syncthreads();
    if (tid < 1024) h[tid] = 0;
    __syncthreads();
#pragma unroll
    for (int i = 0; i < 32; ++i)
      if ((bv[i] >> 10) == p2) atomicAdd(&h[bv[i] & 1023], 1);
    __syncthreads();
    if (tid < 256) {
      int gs = 0;
#pragma unroll
      for (int j = 0; j < 4; ++j) gs += h[tid * 4 + j];
      gsum[tid] = gs;
    }
    __syncthreads();
    if (tid == 0) {
      int run = 0, gidx = 255;
      for (; gidx >= 0; --gidx) { if (run + gsum[gidx] >= k) break; run += gsum[gidx]; }
      if (gidx < 0) { sT = -1.0f; }
      else {
        int bin = gidx * 4 + 3;
        for (; bin > gidx * 4; --bin) { if (run + h[bin] >= k) break; run += h[bin]; }
        sT = __uint_as_float((p2 << 10) | (unsigned)bin);
        sR = k - run;
      }
    }
    __syncthreads();
  }

  // ---- bg sum over threshold (+ r*T) ----
  float T = sT;
  float ls = 0.f;
#pragma unroll
  for (int i = 0; i < 32; ++i) {
    float v = __uint_as_float(bv[i]);
    if (v > T) ls += v;   // sentinel 0.0 adds exactly 0 when T<0
  }
  for (int off = 32; off; off >>= 1) ls += __shfl_xor(ls, off);
  if ((tid & 63) == 0) sd[tid >> 6] = (double)ls;
  __syncthreads();
  if (tid == 0) {
    double tt = 0.0;
    for (int w = 0; w < 16; ++w) tt += sd[w];
    if (sR > 0) tt += (double)sR * (double)sT;
    if (tt != 0.0) atomicAdd(&acc[2], tt);
    __threadfence();
    if (atomicAdd(ticket, 1) == B - 1) {
      // last block: finalize. acc[0..1]/num_fg written in a previous
      // dispatch (visible); acc[2] written by sibling blocks -> atomic read.
      int tot = 0;
      for (int bb = 0; bb < B; ++bb) tot += num_fg[bb];
      double N = (double)(tot > 1 ? tot : 1);
      double a2 = atomicAdd(&acc[2], 0.0);
      out[0] = (float)(2.0 * acc[0] / N);
      out[1] = (float)((acc[1] + a2) / N);
    }
  }
}

extern "C" void kernel_launch(void* const* d_in, const int* in_sizes, int n_in,
                              void* d_out, int out_size, void* d_ws, size_t ws_size,
                              hipStream_t stream) {
  const float4* logit4  = (const float4*)d_in[0];
  const float4* reg     = (const float4*)d_in[1];
  const float4* anchors = (const float4*)d_in[2];
  const float4* gtb     = (const float4*)d_in[3];
  const int*    gtl     = (const int*)d_in[4];

  char* ws = (char*)d_ws;
  int*      matched = (int*)(ws + offMatched);
  unsigned* cbits   = (unsigned*)(ws + offBits);
  int*      numfg   = (int*)(ws + offNumFg);
  double*   acc     = (double*)(ws + offAcc);
  int*      tick    = (int*)(ws + offTick);
  ull*      gtpack  = (ull*)(ws + offGt);
  float*    out     = (float*)d_out;

  init_kernel<<<8, 256, 0, stream>>>((int*)(ws + offNumFg), gtpack);
  match_kernel<<<dim3(A / 256, B), 256, 0, stream>>>(anchors, gtb, matched, gtpack);
  force_kernel<<<1, 64, 0, stream>>>(gtpack, matched);
  loss_kernel<<<dim3(A / (APB * NT), B), 256, 0, stream>>>(
      logit4, reg, anchors, gtb, gtl, matched, cbits, numfg, acc);
  select_fused<<<B, 1024, 0, stream>>>(cbits, numfg, acc, tick + 1, out);
}